// Round 5
// baseline (1885.459 us; speedup 1.0000x reference)
//
#include <hip/hip_runtime.h>
#include <cmath>
#include <utility>

#pragma clang fp contract(off)

#define B_TOTAL 16384
#define STATE 24
#define NIN 48            // 2*STATE encoded channels
#define HID 128
#define ACT 4
#define T_STEPS 40
#define RPG 8             // rows per rowgroup
#define GRPS 8            // rowgroups per block
#define ROWS_PER_BLOCK (RPG * GRPS)

typedef unsigned long long u64;
typedef unsigned int u32;

// f64 dynamics to match the numpy (f64) reference through 40 chaotic threshold
// steps. Spike masks are wave-uniform ballots held in SGPRs; synaptic matmul is
// a masked f64 add: per (row,bit) = 1.5 SALU (shared-shift sign extract) +
// 2x v_and_b32 (SGPR-sourced) + v_add_f64. Weights live in LDS as fp32 pairs
// (cvt to f64 once per pair per wave). One barrier per step via triple-buffered
// ballot exchange. 1024 thr = 8 rowgroups x 128 hidden; 8 rows/thread.

// ---- masked-add window, bit indices as compile-time constants ----
template<int BASE, int JJ>
__device__ __forceinline__ void win_pair(double (&ci)[RPG], const u32 (&sm)[RPG],
                                         const float* __restrict__ wt2h) {
    const float2 wv = *reinterpret_cast<const float2*>(wt2h + ((BASE + JJ) >> 1) * (2 * HID));
    const double w0 = (double)wv.x, w1 = (double)wv.y;   // exact cvt
    const int w0lo = __double2loint(w0), w0hi = __double2hiint(w0);
    const int w1lo = __double2loint(w1), w1hi = __double2hiint(w1);
#pragma unroll
    for (int r = 0; r < RPG; ++r) {
        const u32 a = sm[r] << (30 - JJ);        // bits JJ+1,JJ at positions 31,30
        const int s1 = (int)a >> 31;             // sign mask for bit JJ+1
        const int s0 = (int)(a << 1) >> 31;      // sign mask for bit JJ
        ci[r] += __hiloint2double(w0hi & s0, w0lo & s0);
        ci[r] += __hiloint2double(w1hi & s1, w1lo & s1);
    }
}

template<int BASE, int... I>
__device__ __forceinline__ void win_impl(double (&ci)[RPG], const u32 (&sm)[RPG],
                                         const float* __restrict__ wt2h,
                                         std::integer_sequence<int, I...>) {
    ((void)win_pair<BASE, 2 * I>(ci, sm, wt2h), ...);
}

template<int BASE, int CNT>
__device__ __forceinline__ void win(double (&ci)[RPG], const u32 (&sm)[RPG],
                                    const float* __restrict__ wt2h) {
    win_impl<BASE>(ci, sm, wt2h, std::make_integer_sequence<int, CNT / 2>{});
}

__global__ __launch_bounds__(1024, 4) void snn_fused_f64(
    const float* __restrict__ x, const float* __restrict__ w_in,
    const float* __restrict__ w_rec, const float* __restrict__ w_out,
    float* __restrict__ out)
{
    __shared__ float WT2[(NIN + HID) * HID];   // 90112 B, pair-interleaved W^T
    __shared__ u64 enc[T_STEPS][GRPS][RPG];    // 20480 B, input spike masks
    __shared__ u64 ball[3][GRPS][RPG][2];      // 3072 B, z ballots, triple-buf

    const int tid = threadIdx.x;

    // ---- stage pair-interleaved transposed weights: WT2[(j>>1)*256 + 2h + (j&1)] ----
    for (int idx = tid; idx < NIN * HID; idx += 1024) {
        int hh = idx / NIN, jj = idx - hh * NIN;          // w_in[hh][jj]
        WT2[(jj >> 1) * (2 * HID) + 2 * hh + (jj & 1)] = w_in[idx];
    }
    for (int idx = tid; idx < HID * HID; idx += 1024) {
        int hh = idx >> 7, jj = idx & 127;                // w_rec[hh][jj]
        int j = NIN + jj;
        WT2[(j >> 1) * (2 * HID) + 2 * hh + (j & 1)] = w_rec[idx];
    }
    {   // zero ballot buffers (t=0 reads buffer 2 as z_old = 0)
        u64* bp = &ball[0][0][0][0];
        for (int i = tid; i < 3 * GRPS * RPG * 2; i += 1024) bp[i] = 0ull;
    }

    const int g    = tid >> 7;          // rowgroup 0..7
    const int h    = tid & 127;         // hidden unit
    const int lane = tid & 63;
    const int hv   = (tid >> 6) & 1;    // wave half: 0 => h<64
    const int row0 = blockIdx.x * ROWS_PER_BLOCK + g * RPG;

    const double DTM = 0.1;
    const double KS  = 1.0 - 0.2;       // == 0.8 in f64, same as np

    // ---- encoder precompute (hv==0 wave of each rowgroup; lane==channel) ----
    if (hv == 0) {
        double cc[RPG], e[RPG];
#pragma unroll
        for (int r = 0; r < RPG; ++r) {
            double cur = 0.0;
            if (lane < STATE)    cur = fmax( 50.0 * (double)x[(row0 + r) * STATE + lane], 0.0);
            else if (lane < NIN) cur = fmax(-50.0 * (double)x[(row0 + r) * STATE + lane - STATE], 0.0);
            cc[r] = cur; e[r] = 0.0;
        }
        for (int t = 0; t < T_STEPS; ++t) {
#pragma unroll
            for (int r = 0; r < RPG; ++r) {
                double en = e[r] + DTM * (cc[r] - e[r]);
                bool sp = en > 1.0;
                u64 m = __ballot(sp);
                e[r] = sp ? 0.0 : en;
                if (lane == 0) enc[t][g][r] = m;
            }
        }
    }

    // w_out columns (fp32 regs; cvt to f64 at use is exact)
    float wo0[ACT], wo1[ACT];
#pragma unroll
    for (int a = 0; a < ACT; ++a) {
        wo0[a] = w_out[a * HID + lane];
        wo1[a] = w_out[a * HID + 64 + lane];
    }

    double v[RPG], ci[RPG];
#pragma unroll
    for (int r = 0; r < RPG; ++r) { v[r] = 0.0; ci[r] = 0.0; }
    double li_v = 0.0, li_i = 0.0, mx = -1e300;
    const int rbase = hv * 4;           // this wave's readout rows
    const float* wt2h = &WT2[2 * h];    // per-thread weight column base

    __syncthreads();

    for (int t = 0; t < T_STEPS; ++t) {
        const int wb = t % 3;           // write buffer (z_new)
        const int rb = (t + 2) % 3;     // read buffer  (z_old, step t-1)

        // ---- LIF decay + threshold -> publish z_new ballots ----
#pragma unroll
        for (int r = 0; r < RPG; ++r) {
            double vd = v[r] + DTM * (ci[r] - v[r]);
            ci[r] = KS * ci[r];
            bool z = vd > 1.0;
            u64 m = __ballot(z);
            v[r] = z ? 0.0 : vd;
            if (lane == 0) ball[wb][g][r][hv] = m;
        }
        __syncthreads();                // only barrier per step

        // ---- LI readout: rows split across the two waves (hv0: 0-3, hv1: 4-7) ----
#pragma unroll
        for (int rr = 0; rr < 4; ++rr) {
            int r = rbase + rr;
            u64 mlo = ball[wb][g][r][0];
            u64 mhi = ball[wb][g][r][1];
            bool b0 = (mlo >> lane) & 1ull;
            bool b1 = (mhi >> lane) & 1ull;
            double u[ACT];
#pragma unroll
            for (int a = 0; a < ACT; ++a) {
                double p = (double)(b0 ? wo0[a] : 0.f) + (double)(b1 ? wo1[a] : 0.f);
#pragma unroll
                for (int off = 32; off > 0; off >>= 1)
                    p += __shfl_xor(p, off, 64);
                u[a] = p;
            }
            if (lane < 16 && (lane >> 2) == rr) {
                double um = (lane & 1) ? ((lane & 2) ? u[3] : u[1])
                                       : ((lane & 2) ? u[2] : u[0]);
                double ij = li_i + um;
                li_v = li_v + DTM * (ij - li_v);
                li_i = KS * ij;
                mx = fmax(mx, li_v);
            }
        }

        // ---- synaptic input: ci[r] += sum_j mask(r,j) * W[j][h] (f64 masked add) ----
        {
            const u32* encp  = (const u32*)&enc[t][g][0];       // row stride 2 u32
            const u32* ballp = (const u32*)&ball[rb][g][0][0];  // row stride 4 u32
            u32 sm[RPG];
            auto loadsm = [&](const u32* p, int stride, int off) {
#pragma unroll
                for (int r = 0; r < RPG; ++r)
                    sm[r] = (u32)__builtin_amdgcn_readfirstlane((int)p[stride * r + off]);
            };
            loadsm(encp,  2, 0); win<0,   32>(ci, sm, wt2h);  // input ch 0..31
            loadsm(encp,  2, 1); win<32,  16>(ci, sm, wt2h);  // input ch 32..47
            loadsm(ballp, 4, 0); win<48,  32>(ci, sm, wt2h);  // recurrent h 0..31
            loadsm(ballp, 4, 1); win<80,  32>(ci, sm, wt2h);  // recurrent h 32..63
            loadsm(ballp, 4, 2); win<112, 32>(ci, sm, wt2h);  // recurrent h 64..95
            loadsm(ballp, 4, 3); win<144, 32>(ci, sm, wt2h);  // recurrent h 96..127
        }
        // no second barrier: z_old ballots are triple-buffered
        // (writer of buffer b at step t+3 is post-barrier-(t+2); readers at
        //  step t finish before barrier-(t+1) — ordered by the barriers between)
    }

    if (lane < 16) {
        // lane = (rr<<2)|a -> out[(row0+rbase+rr)*4 + a]
        out[(row0 + rbase) * ACT + lane] = (float)tanh(mx);
    }
}

extern "C" void kernel_launch(void* const* d_in, const int* in_sizes, int n_in,
                              void* d_out, int out_size, void* d_ws, size_t ws_size,
                              hipStream_t stream) {
    (void)in_sizes; (void)n_in; (void)out_size; (void)d_ws; (void)ws_size;
    const float* x     = (const float*)d_in[0];
    const float* w_in  = (const float*)d_in[1];
    const float* w_rec = (const float*)d_in[2];
    const float* w_out = (const float*)d_in[3];
    float* out = (float*)d_out;
    snn_fused_f64<<<B_TOTAL / ROWS_PER_BLOCK, 1024, 0, stream>>>(x, w_in, w_rec, w_out, out);
}

// Round 6
// 1672.529 us; speedup vs baseline: 1.1273x; 1.1273x over previous
//
#include <hip/hip_runtime.h>
#include <cmath>
#include <utility>

#pragma clang fp contract(off)

#define B_TOTAL 16384
#define STATE 24
#define NIN 48            // 2*STATE encoded channels
#define HID 128
#define ACT 4
#define T_STEPS 40
#define RPG 8             // rows per rowgroup
#define GRPS 8            // rowgroups per block
#define ROWS_PER_BLOCK (RPG * GRPS)

typedef unsigned long long u64;
typedef unsigned int u32;

// f64 dynamics (spike-exact vs np reference), f32 LI readout (no thresholds
// downstream -> f32 error ~3e-5 invisible at bf16/0.02 comparison).
// Spike masks: wave-uniform ballots in SGPRs. Synaptic matmul: masked f64 add,
// per (row,bit) = 1.5 SALU sign-extract + 2x v_and_b32 + v_add_f64.
// amdgpu_waves_per_eu(4,4): LDS caps us at 1 block/CU (16 waves = 4/EU) anyway;
// without it the compiler targeted 8/EU, chose 64 VGPRs and spilled ~1.9 GB/launch.

template<int BASE, int JJ>
__device__ __forceinline__ void win_pair(double (&ci)[RPG], const u32 (&sm)[RPG],
                                         const float* __restrict__ wt2h) {
    const float2 wv = *reinterpret_cast<const float2*>(wt2h + ((BASE + JJ) >> 1) * (2 * HID));
    const double w0 = (double)wv.x, w1 = (double)wv.y;   // exact cvt
    const int w0lo = __double2loint(w0), w0hi = __double2hiint(w0);
    const int w1lo = __double2loint(w1), w1hi = __double2hiint(w1);
#pragma unroll
    for (int r = 0; r < RPG; ++r) {
        const u32 a = sm[r] << (30 - JJ);        // bits JJ+1,JJ at positions 31,30
        const int s1 = (int)a >> 31;             // sign mask for bit JJ+1
        const int s0 = (int)(a << 1) >> 31;      // sign mask for bit JJ
        ci[r] += __hiloint2double(w0hi & s0, w0lo & s0);
        ci[r] += __hiloint2double(w1hi & s1, w1lo & s1);
    }
}

template<int BASE, int... I>
__device__ __forceinline__ void win_impl(double (&ci)[RPG], const u32 (&sm)[RPG],
                                         const float* __restrict__ wt2h,
                                         std::integer_sequence<int, I...>) {
    ((void)win_pair<BASE, 2 * I>(ci, sm, wt2h), ...);
}

template<int BASE, int CNT>
__device__ __forceinline__ void win(double (&ci)[RPG], const u32 (&sm)[RPG],
                                    const float* __restrict__ wt2h) {
    win_impl<BASE>(ci, sm, wt2h, std::make_integer_sequence<int, CNT / 2>{});
}

__global__ __launch_bounds__(1024)
__attribute__((amdgpu_waves_per_eu(4, 4)))
void snn_fused_f64(
    const float* __restrict__ x, const float* __restrict__ w_in,
    const float* __restrict__ w_rec, const float* __restrict__ w_out,
    float* __restrict__ out)
{
    __shared__ float WT2[(NIN + HID) * HID];   // 90112 B, pair-interleaved W^T
    __shared__ u64 enc[T_STEPS][GRPS][RPG];    // 20480 B, input spike masks
    __shared__ u64 ball[3][GRPS][RPG][2];      // 3072 B, z ballots, triple-buf

    const int tid = threadIdx.x;

    // ---- stage pair-interleaved transposed weights: WT2[(j>>1)*256 + 2h + (j&1)] ----
    for (int idx = tid; idx < NIN * HID; idx += 1024) {
        int hh = idx / NIN, jj = idx - hh * NIN;          // w_in[hh][jj]
        WT2[(jj >> 1) * (2 * HID) + 2 * hh + (jj & 1)] = w_in[idx];
    }
    for (int idx = tid; idx < HID * HID; idx += 1024) {
        int hh = idx >> 7, jj = idx & 127;                // w_rec[hh][jj]
        int j = NIN + jj;
        WT2[(j >> 1) * (2 * HID) + 2 * hh + (j & 1)] = w_rec[idx];
    }
    {   // zero ballot buffers (t=0 reads buffer 2 as z_old = 0)
        u64* bp = &ball[0][0][0][0];
        for (int i = tid; i < 3 * GRPS * RPG * 2; i += 1024) bp[i] = 0ull;
    }

    const int g    = tid >> 7;          // rowgroup 0..7
    const int h    = tid & 127;         // hidden unit
    const int lane = tid & 63;
    const int hv   = (tid >> 6) & 1;    // wave half: 0 => h<64
    const int row0 = blockIdx.x * ROWS_PER_BLOCK + g * RPG;

    const double DTM = 0.1;
    const double KS  = 1.0 - 0.2;       // == 0.8 in f64, same as np

    // ---- encoder precompute, f64 (thresholds -> must be spike-exact) ----
    if (hv == 0) {
        double cc[RPG], e[RPG];
#pragma unroll
        for (int r = 0; r < RPG; ++r) {
            double cur = 0.0;
            if (lane < STATE)    cur = fmax( 50.0 * (double)x[(row0 + r) * STATE + lane], 0.0);
            else if (lane < NIN) cur = fmax(-50.0 * (double)x[(row0 + r) * STATE + lane - STATE], 0.0);
            cc[r] = cur; e[r] = 0.0;
        }
        for (int t = 0; t < T_STEPS; ++t) {
#pragma unroll
            for (int r = 0; r < RPG; ++r) {
                double en = e[r] + DTM * (cc[r] - e[r]);
                bool sp = en > 1.0;
                u64 m = __ballot(sp);
                e[r] = sp ? 0.0 : en;
                if (lane == 0) enc[t][g][r] = m;
            }
        }
    }

    // w_out columns (f32 readout path)
    float wo0[ACT], wo1[ACT];
#pragma unroll
    for (int a = 0; a < ACT; ++a) {
        wo0[a] = w_out[a * HID + lane];
        wo1[a] = w_out[a * HID + 64 + lane];
    }

    double v[RPG], ci[RPG];
#pragma unroll
    for (int r = 0; r < RPG; ++r) { v[r] = 0.0; ci[r] = 0.0; }
    float li_v = 0.f, li_i = 0.f, mx = -1e30f;
    const int rbase = hv * 4;           // this wave's readout rows
    const float* wt2h = &WT2[2 * h];    // per-thread weight column base

    __syncthreads();

    for (int t = 0; t < T_STEPS; ++t) {
        const int wb = t % 3;           // write buffer (z_new)
        const int rb = (t + 2) % 3;     // read buffer  (z_old, step t-1)

        // ---- LIF decay + threshold -> publish z_new ballots (f64, spike-exact) ----
#pragma unroll
        for (int r = 0; r < RPG; ++r) {
            double vd = v[r] + DTM * (ci[r] - v[r]);
            ci[r] = KS * ci[r];
            bool z = vd > 1.0;
            u64 m = __ballot(z);
            v[r] = z ? 0.0 : vd;
            if (lane == 0) ball[wb][g][r][hv] = m;
        }
        __syncthreads();                // only barrier per step

        // ---- LI readout (f32): rows split across the two waves ----
#pragma unroll
        for (int rr = 0; rr < 4; ++rr) {
            int r = rbase + rr;
            u64 mlo = ball[wb][g][r][0];
            u64 mhi = ball[wb][g][r][1];
            bool b0 = (mlo >> lane) & 1ull;
            bool b1 = (mhi >> lane) & 1ull;
            float u[ACT];
#pragma unroll
            for (int a = 0; a < ACT; ++a) {
                float p = (b0 ? wo0[a] : 0.f) + (b1 ? wo1[a] : 0.f);
#pragma unroll
                for (int off = 32; off > 0; off >>= 1)
                    p += __shfl_xor(p, off, 64);
                u[a] = p;
            }
            if (lane < 16 && (lane >> 2) == rr) {
                float um = (lane & 1) ? ((lane & 2) ? u[3] : u[1])
                                      : ((lane & 2) ? u[2] : u[0]);
                float ij = li_i + um;
                li_v = li_v + 0.1f * (ij - li_v);
                li_i = 0.8f * ij;
                mx = fmaxf(mx, li_v);
            }
        }

        // ---- synaptic input: ci[r] += sum_j mask(r,j) * W[j][h] (f64 masked add) ----
        {
            const u32* encp  = (const u32*)&enc[t][g][0];       // row stride 2 u32
            const u32* ballp = (const u32*)&ball[rb][g][0][0];  // row stride 4 u32
            u32 sm[RPG];
            auto loadsm = [&](const u32* p, int stride, int off) {
#pragma unroll
                for (int r = 0; r < RPG; ++r)
                    sm[r] = (u32)__builtin_amdgcn_readfirstlane((int)p[stride * r + off]);
            };
            loadsm(encp,  2, 0); win<0,   32>(ci, sm, wt2h);  // input ch 0..31
            loadsm(encp,  2, 1); win<32,  16>(ci, sm, wt2h);  // input ch 32..47
            loadsm(ballp, 4, 0); win<48,  32>(ci, sm, wt2h);  // recurrent h 0..31
            loadsm(ballp, 4, 1); win<80,  32>(ci, sm, wt2h);  // recurrent h 32..63
            loadsm(ballp, 4, 2); win<112, 32>(ci, sm, wt2h);  // recurrent h 64..95
            loadsm(ballp, 4, 3); win<144, 32>(ci, sm, wt2h);  // recurrent h 96..127
        }
        // no second barrier: z_old ballots are triple-buffered
        // (writer of buffer b at step t+3 is post-barrier-(t+2); readers at
        //  step t finish before barrier-(t+1) — ordered by the barriers between)
    }

    if (lane < 16) {
        // lane = (rr<<2)|a -> out[(row0+rbase+rr)*4 + a]
        out[(row0 + rbase) * ACT + lane] = tanhf(mx);
    }
}

extern "C" void kernel_launch(void* const* d_in, const int* in_sizes, int n_in,
                              void* d_out, int out_size, void* d_ws, size_t ws_size,
                              hipStream_t stream) {
    (void)in_sizes; (void)n_in; (void)out_size; (void)d_ws; (void)ws_size;
    const float* x     = (const float*)d_in[0];
    const float* w_in  = (const float*)d_in[1];
    const float* w_rec = (const float*)d_in[2];
    const float* w_out = (const float*)d_in[3];
    float* out = (float*)d_out;
    snn_fused_f64<<<B_TOTAL / ROWS_PER_BLOCK, 1024, 0, stream>>>(x, w_in, w_rec, w_out, out);
}

// Round 10
// 1620.809 us; speedup vs baseline: 1.1633x; 1.0319x over previous
//
#include <hip/hip_runtime.h>
#include <cmath>

#pragma clang fp contract(off)

#define B_TOTAL 16384
#define STATE 24
#define NIN 48            // 2*STATE encoded channels
#define HID 128
#define ACT 4
#define T_STEPS 40
#define RPG 8             // rows per rowgroup
#define GRPS 8            // rowgroups per block
#define ROWS_PER_BLOCK (RPG * GRPS)

typedef unsigned long long u64;
typedef unsigned int u32;

// f64 dynamics (spike-exact vs np f64 reference; absmax = 1 bf16 ulp when
// correct), f32 LI readout (no thresholds downstream). Spike masks are
// wave-uniform ballots in SGPRs; synaptic matmul = masked f64 add:
// per (row,bit) ~1.5 SALU sign-extract + 2x v_and_b32 + v_add_f64.
// Runtime pair-loop with unroll 2 keeps live temporaries bounded (~65 regs).
//
// __launch_bounds__(1024, 1): EMPIRICAL — (1024,4) gave VGPR budget 64 + 1.4GB
// spill traffic (R5/R6 counters): CUDA min-BLOCKS semantics -> 64 waves/CU ->
// clamp 8 waves/SIMD -> 512-reg SIMD pool / 8 = 64 VGPRs. With min=1 the block
// shape itself (16 waves = 4/SIMD) forces V <= 512/4 = 128 under EITHER
// semantics -> 128-VGPR budget, no spills. LDS (113KB) caps 1 block/CU anyway.

__device__ __forceinline__ void window_rt(double (&ci)[RPG], const u32 (&sm)[RPG],
                                          const float* __restrict__ wt2h,
                                          int base, int cnt) {
    // weights for bits (base+jj, base+jj+1) at wt2h[((base+jj)>>1)*256 + {0,1}]
#pragma unroll 2
    for (int jj = 0; jj < cnt; jj += 2) {
        const float2 wv = *reinterpret_cast<const float2*>(wt2h + ((base + jj) >> 1) * (2 * HID));
        const double w0 = (double)wv.x, w1 = (double)wv.y;   // exact cvt
        const int w0lo = __double2loint(w0), w0hi = __double2hiint(w0);
        const int w1lo = __double2loint(w1), w1hi = __double2hiint(w1);
        const int sh = 30 - jj;
#pragma unroll
        for (int r = 0; r < RPG; ++r) {
            const u32 a = sm[r] << sh;           // bits jj+1,jj at positions 31,30
            const int s1 = (int)a >> 31;         // sign mask for bit jj+1
            const int s0 = (int)(a << 1) >> 31;  // sign mask for bit jj
            ci[r] += __hiloint2double(w0hi & s0, w0lo & s0);
            ci[r] += __hiloint2double(w1hi & s1, w1lo & s1);
        }
    }
}

__global__ __launch_bounds__(1024, 1) void snn_fused_f64(
    const float* __restrict__ x, const float* __restrict__ w_in,
    const float* __restrict__ w_rec, const float* __restrict__ w_out,
    float* __restrict__ out)
{
    __shared__ float WT2[(NIN + HID) * HID];   // 90112 B, pair-interleaved W^T
    __shared__ u64 enc[T_STEPS][GRPS][RPG];    // 20480 B, input spike masks
    __shared__ u64 ball[3][GRPS][RPG][2];      // 3072 B, z ballots, triple-buf

    const int tid = threadIdx.x;

    // ---- stage pair-interleaved transposed weights: WT2[(j>>1)*256 + 2h + (j&1)] ----
    for (int idx = tid; idx < NIN * HID; idx += 1024) {
        int hh = idx / NIN, jj = idx - hh * NIN;          // w_in[hh][jj]
        WT2[(jj >> 1) * (2 * HID) + 2 * hh + (jj & 1)] = w_in[idx];
    }
    for (int idx = tid; idx < HID * HID; idx += 1024) {
        int hh = idx >> 7, jj = idx & 127;                // w_rec[hh][jj]
        int j = NIN + jj;
        WT2[(j >> 1) * (2 * HID) + 2 * hh + (j & 1)] = w_rec[idx];
    }
    {   // zero ballot buffers (t=0 reads buffer 2 as z_old = 0)
        u64* bp = &ball[0][0][0][0];
        for (int i = tid; i < 3 * GRPS * RPG * 2; i += 1024) bp[i] = 0ull;
    }

    const int g    = tid >> 7;          // rowgroup 0..7
    const int h    = tid & 127;         // hidden unit
    const int lane = tid & 63;
    const int hv   = (tid >> 6) & 1;    // wave half: 0 => h<64
    const int row0 = blockIdx.x * ROWS_PER_BLOCK + g * RPG;

    const double DTM = 0.1;
    const double KS  = 1.0 - 0.2;       // == 0.8 in f64, same as np

    // ---- encoder precompute, f64 (thresholds -> must be spike-exact) ----
    if (hv == 0) {
        double cc[RPG], e[RPG];
#pragma unroll
        for (int r = 0; r < RPG; ++r) {
            double cur = 0.0;
            if (lane < STATE)    cur = fmax( 50.0 * (double)x[(row0 + r) * STATE + lane], 0.0);
            else if (lane < NIN) cur = fmax(-50.0 * (double)x[(row0 + r) * STATE + lane - STATE], 0.0);
            cc[r] = cur; e[r] = 0.0;
        }
        for (int t = 0; t < T_STEPS; ++t) {
#pragma unroll
            for (int r = 0; r < RPG; ++r) {
                double en = e[r] + DTM * (cc[r] - e[r]);
                bool sp = en > 1.0;
                u64 m = __ballot(sp);
                e[r] = sp ? 0.0 : en;
                if (lane == 0) enc[t][g][r] = m;
            }
        }
    }

    // w_out columns (f32 readout path)
    float wo0[ACT], wo1[ACT];
#pragma unroll
    for (int a = 0; a < ACT; ++a) {
        wo0[a] = w_out[a * HID + lane];
        wo1[a] = w_out[a * HID + 64 + lane];
    }

    double v[RPG], ci[RPG];
#pragma unroll
    for (int r = 0; r < RPG; ++r) { v[r] = 0.0; ci[r] = 0.0; }
    float li_v = 0.f, li_i = 0.f, mx = -1e30f;
    const int rbase = hv * 4;           // this wave's readout rows
    const float* wt2h = &WT2[2 * h];    // per-thread weight column base

    __syncthreads();

    for (int t = 0; t < T_STEPS; ++t) {
        const int wb = t % 3;           // write buffer (z_new)
        const int rb = (t + 2) % 3;     // read buffer  (z_old, step t-1)

        // ---- LIF decay + threshold -> publish z_new ballots (f64, spike-exact) ----
#pragma unroll
        for (int r = 0; r < RPG; ++r) {
            double vd = v[r] + DTM * (ci[r] - v[r]);
            ci[r] = KS * ci[r];
            bool z = vd > 1.0;
            u64 m = __ballot(z);
            v[r] = z ? 0.0 : vd;
            if (lane == 0) ball[wb][g][r][hv] = m;
        }
        __syncthreads();                // only barrier per step

        // ---- LI readout (f32): rows split across the two waves ----
#pragma unroll
        for (int rr = 0; rr < 4; ++rr) {
            int r = rbase + rr;
            u64 mlo = ball[wb][g][r][0];
            u64 mhi = ball[wb][g][r][1];
            bool b0 = (mlo >> lane) & 1ull;
            bool b1 = (mhi >> lane) & 1ull;
            float u[ACT];
#pragma unroll
            for (int a = 0; a < ACT; ++a) {
                float p = (b0 ? wo0[a] : 0.f) + (b1 ? wo1[a] : 0.f);
#pragma unroll
                for (int off = 32; off > 0; off >>= 1)
                    p += __shfl_xor(p, off, 64);
                u[a] = p;
            }
            if (lane < 16 && (lane >> 2) == rr) {
                float um = (lane & 1) ? ((lane & 2) ? u[3] : u[1])
                                      : ((lane & 2) ? u[2] : u[0]);
                float ij = li_i + um;
                li_v = li_v + 0.1f * (ij - li_v);
                li_i = 0.8f * ij;
                mx = fmaxf(mx, li_v);
            }
        }

        // ---- synaptic input: ci[r] += sum_j mask(r,j) * W[j][h] (f64 masked add) ----
        {
            const u32* encp  = (const u32*)&enc[t][g][0];       // row stride 2 u32
            const u32* ballp = (const u32*)&ball[rb][g][0][0];  // row stride 4 u32
            u32 sm[RPG];
            auto loadsm = [&](const u32* p, int stride, int off) {
#pragma unroll
                for (int r = 0; r < RPG; ++r)
                    sm[r] = (u32)__builtin_amdgcn_readfirstlane((int)p[stride * r + off]);
            };
            loadsm(encp,  2, 0); window_rt(ci, sm, wt2h, 0,   32);  // input ch 0..31
            loadsm(encp,  2, 1); window_rt(ci, sm, wt2h, 32,  16);  // input ch 32..47
            loadsm(ballp, 4, 0); window_rt(ci, sm, wt2h, 48,  32);  // recurrent h 0..31
            loadsm(ballp, 4, 1); window_rt(ci, sm, wt2h, 80,  32);  // recurrent h 32..63
            loadsm(ballp, 4, 2); window_rt(ci, sm, wt2h, 112, 32);  // recurrent h 64..95
            loadsm(ballp, 4, 3); window_rt(ci, sm, wt2h, 144, 32);  // recurrent h 96..127
        }
        // no second barrier: z_old ballots are triple-buffered
        // (writer of buffer b at step t+3 is post-barrier-(t+2); readers at
        //  step t finish before barrier-(t+1) — ordered by the barriers between)
    }

    if (lane < 16) {
        // lane = (rr<<2)|a -> out[(row0+rbase+rr)*4 + a]
        out[(row0 + rbase) * ACT + lane] = tanhf(mx);
    }
}

extern "C" void kernel_launch(void* const* d_in, const int* in_sizes, int n_in,
                              void* d_out, int out_size, void* d_ws, size_t ws_size,
                              hipStream_t stream) {
    (void)in_sizes; (void)n_in; (void)out_size; (void)d_ws; (void)ws_size;
    const float* x     = (const float*)d_in[0];
    const float* w_in  = (const float*)d_in[1];
    const float* w_rec = (const float*)d_in[2];
    const float* w_out = (const float*)d_in[3];
    float* out = (float*)d_out;
    snn_fused_f64<<<B_TOTAL / ROWS_PER_BLOCK, 1024, 0, stream>>>(x, w_in, w_rec, w_out, out);
}